// Round 2
// baseline (568.156 us; speedup 1.0000x reference)
//
#include <hip/hip_runtime.h>

typedef float f32x4 __attribute__((ext_vector_type(4)));
typedef __bf16 bf16x8 __attribute__((ext_vector_type(8)));

#define IMH 256
#define IMW 256
#define NCH 128
#define NHEAD 4
#define NWIN 1024
#define DWIN 2048
#define HW (IMH*IMW)

__device__ __forceinline__ unsigned short bf16u(float f) {
  __bf16 h = (__bf16)f;
  return __builtin_bit_cast(unsigned short, h);
}
__device__ __forceinline__ f32x4 fzero() { f32x4 z = {0.f, 0.f, 0.f, 0.f}; return z; }

// ---------------- prep: weights -> bf16 ----------------
__global__ void k_prep_w(const float* __restrict__ wq, const float* __restrict__ wk,
                         const float* __restrict__ wv, __bf16* __restrict__ wt) {
  int i = blockIdx.x * 256 + threadIdx.x;
  if (i < 16384) {
    wt[i]         = (__bf16)wq[i];
    wt[i + 16384] = (__bf16)wk[i];
    wt[i + 32768] = (__bf16)wv[i];
  }
}

// wo [o][c][3][3] -> wot [ky*3+kx][o][c]
__global__ void k_prep_wo(const float* __restrict__ wo, __bf16* __restrict__ wot) {
  int i = blockIdx.x * 256 + threadIdx.x;
  if (i < 9*16384) {
    int kk = i >> 14;
    int oc = i & 16383;
    wot[i] = (__bf16)wo[oc*9 + kk];
  }
}

// ---------------- qkv projection: one image row per block ----------------
__global__ __launch_bounds__(512)
void k_qkv(const float* __restrict__ x, const __bf16* __restrict__ wt,
           const float* __restrict__ bq, const float* __restrict__ bk,
           const float* __restrict__ bv,
           __bf16* __restrict__ qw, __bf16* __restrict__ kw, __bf16* __restrict__ vt) {
  __shared__ __align__(16) unsigned short xt[256*128];   // [w][c] swizzled, 64KB
  const int bidx = blockIdx.x;
  const int b = bidx >> 8, h = bidx & 255;
  const int py = h & 7, oy = h >> 3;
  const int t = threadIdx.x;
  // stage x^T (bf16) with XOR swizzle: byte = w*256 + ((c*2) ^ ((w&7)<<4))
  {
    const int w = t & 255, half = t >> 8;
    const float* xb = x + (size_t)(b*NCH)*HW + (size_t)h*IMW + w;
    #pragma unroll 8
    for (int i = 0; i < 32; ++i) {
      int c = half*64 + 2*i;
      float v0 = xb[(size_t)c*HW];
      float v1 = xb[(size_t)(c+1)*HW];
      unsigned int pk = (unsigned int)bf16u(v0) | ((unsigned int)bf16u(v1) << 16);
      *(unsigned int*)((char*)xt + (w*256 + ((c*2) ^ ((w&7)<<4)))) = pk;
    }
  }
  __syncthreads();
  const int lane = t & 63, wid = t >> 6;
  const int wm = wid >> 2, wn = wid & 3;          // o-tile 64*wm, w-tile 64*wn
  const int l15 = lane & 15, l4 = lane >> 4;
  for (int mat = 0; mat < 3; ++mat) {
    const __bf16* wmat = wt + mat*16384;
    const float* bias = (mat == 0) ? bq : ((mat == 1) ? bk : bv);
    f32x4 acc[4][4];
    #pragma unroll
    for (int i = 0; i < 4; ++i)
      #pragma unroll
      for (int j = 0; j < 4; ++j) acc[i][j] = fzero();
    #pragma unroll
    for (int kc = 0; kc < 4; ++kc) {
      bf16x8 a[4], bb[4];
      #pragma unroll
      for (int i = 0; i < 4; ++i) {
        int o = wm*64 + i*16 + l15;
        a[i] = *(const bf16x8*)(wmat + o*128 + kc*32 + l4*8);
      }
      #pragma unroll
      for (int j = 0; j < 4; ++j) {
        int wc = wn*64 + j*16 + l15;
        bb[j] = *(const bf16x8*)((const char*)xt + (wc*256 + ((kc*64 + l4*16) ^ ((wc&7)<<4))));
      }
      #pragma unroll
      for (int i = 0; i < 4; ++i)
        #pragma unroll
        for (int j = 0; j < 4; ++j)
          acc[i][j] = __builtin_amdgcn_mfma_f32_16x16x32_bf16(a[i], bb[j], acc[i][j], 0, 0, 0);
    }
    if (mat < 2) {
      __bf16* dst = (mat == 0) ? qw : kw;
      #pragma unroll
      for (int i = 0; i < 4; ++i)
        #pragma unroll
        for (int r = 0; r < 4; ++r) {
          int o = wm*64 + i*16 + l4*4 + r;
          float bi = bias[o];
          int nh = o >> 5, dk = o & 31;
          #pragma unroll
          for (int j = 0; j < 4; ++j) {
            int wcol = wn*64 + j*16 + l15;
            int ox = wcol >> 3, px = wcol & 7;
            size_t idx = (size_t)((b*NHEAD + nh)*NWIN + oy*32 + ox)*DWIN + dk*64 + py*8 + px;
            dst[idx] = (__bf16)(acc[i][j][r] + bi);
          }
        }
    } else {
      // V: repack through LDS so vt[d][m] rows get 64B contiguous stores
      __syncthreads();
      unsigned short* rp = xt;   // reuse as [o][w] 128x256
      #pragma unroll
      for (int i = 0; i < 4; ++i)
        #pragma unroll
        for (int r = 0; r < 4; ++r) {
          int o = wm*64 + i*16 + l4*4 + r;
          float bi = bias[o];
          #pragma unroll
          for (int j = 0; j < 4; ++j) {
            int wcol = wn*64 + j*16 + l15;
            rp[o*256 + wcol] = bf16u(acc[i][j][r] + bi);
          }
        }
      __syncthreads();
      #pragma unroll
      for (int it = 0; it < 2; ++it) {
        int u = t + it*512;
        int o = u >> 3, px = u & 7;
        int nh = o >> 5, dk = o & 31;
        unsigned short tmp[32];
        #pragma unroll
        for (int ox = 0; ox < 32; ++ox) tmp[ox] = rp[o*256 + ox*8 + px];
        __bf16* dstp = vt + (size_t)((b*NHEAD + nh)*DWIN + dk*64 + py*8 + px)*NWIN + oy*32;
        #pragma unroll
        for (int qq = 0; qq < 4; ++qq) {
          uint4 val;
          val.x = (unsigned int)tmp[qq*8+0] | ((unsigned int)tmp[qq*8+1] << 16);
          val.y = (unsigned int)tmp[qq*8+2] | ((unsigned int)tmp[qq*8+3] << 16);
          val.z = (unsigned int)tmp[qq*8+4] | ((unsigned int)tmp[qq*8+5] << 16);
          val.w = (unsigned int)tmp[qq*8+6] | ((unsigned int)tmp[qq*8+7] << 16);
          ((uint4*)dstp)[qq] = val;
        }
      }
    }
  }
}

// ---------------- shared 128x128 B^T GEMM tile (reg-staged, 2-barrier) ----------------
__device__ __forceinline__ void gemm_tile(const __bf16* __restrict__ A,
                                          const __bf16* __restrict__ B,
                                          const int lda, const int ldb, const int NT,
                                          unsigned short* Asm, unsigned short* Bsm,
                                          f32x4 (&acc)[4][4]) {
  const int t = threadIdx.x;
  const int lane = t & 63, wid = t >> 6;
  const int wm = wid >> 1, wn = wid & 1;
  const int l15 = lane & 15, l4 = lane >> 4;
  const int u0 = t, u1 = t + 256;
  const int ra0 = u0 >> 2, ca0 = u0 & 3;
  const int ra1 = u1 >> 2, ca1 = u1 & 3;
  uint4 ar0 = *(const uint4*)(A + ra0*lda + ca0*8);
  uint4 ar1 = *(const uint4*)(A + ra1*lda + ca1*8);
  uint4 br0 = *(const uint4*)(B + ra0*ldb + ca0*8);
  uint4 br1 = *(const uint4*)(B + ra1*ldb + ca1*8);
  for (int kt = 0; kt < NT; ++kt) {
    __syncthreads();
    *(uint4*)(Asm + u0*8) = ar0;
    *(uint4*)(Asm + u1*8) = ar1;
    *(uint4*)(Bsm + u0*8) = br0;
    *(uint4*)(Bsm + u1*8) = br1;
    __syncthreads();
    if (kt + 1 < NT) {       // issue next-tile loads; latency hides under MFMAs
      int k0 = (kt+1)*32;
      ar0 = *(const uint4*)(A + ra0*lda + k0 + ca0*8);
      ar1 = *(const uint4*)(A + ra1*lda + k0 + ca1*8);
      br0 = *(const uint4*)(B + ra0*ldb + k0 + ca0*8);
      br1 = *(const uint4*)(B + ra1*ldb + k0 + ca1*8);
    }
    bf16x8 a[4], bb[4];
    #pragma unroll
    for (int i = 0; i < 4; ++i)
      a[i] = *(const bf16x8*)((const char*)Asm + (wm*64 + i*16 + l15)*64 + l4*16);
    #pragma unroll
    for (int j = 0; j < 4; ++j)
      bb[j] = *(const bf16x8*)((const char*)Bsm + (wn*64 + j*16 + l15)*64 + l4*16);
    #pragma unroll
    for (int i = 0; i < 4; ++i)
      #pragma unroll
      for (int j = 0; j < 4; ++j)
        acc[i][j] = __builtin_amdgcn_mfma_f32_16x16x32_bf16(a[i], bb[j], acc[i][j], 0, 0, 0);
  }
}

// ---------------- scores = qw . kw^T / sqrt(d) ----------------
__global__ __launch_bounds__(256)
void k_scores(const __bf16* __restrict__ qw, const __bf16* __restrict__ kw,
              float* __restrict__ S) {
  __shared__ __align__(16) unsigned short Asm[4096], Bsm[4096];
  const int bnh = blockIdx.y;
  const int mt = blockIdx.x >> 3, nt = blockIdx.x & 7;
  const __bf16* A = qw + (size_t)bnh*NWIN*DWIN + (size_t)mt*128*DWIN;
  const __bf16* B = kw + (size_t)bnh*NWIN*DWIN + (size_t)nt*128*DWIN;
  f32x4 acc[4][4];
  #pragma unroll
  for (int i = 0; i < 4; ++i)
    #pragma unroll
    for (int j = 0; j < 4; ++j) acc[i][j] = fzero();
  gemm_tile(A, B, DWIN, DWIN, 64, Asm, Bsm, acc);
  const float scale = 0.022097086912079608f;  // 1/sqrt(2048)
  const int t = threadIdx.x, lane = t & 63, wid = t >> 6;
  const int wm = wid >> 1, wn = wid & 1, l15 = lane & 15, l4 = lane >> 4;
  float* Sb = S + (size_t)bnh*NWIN*NWIN + (size_t)(mt*128)*NWIN + nt*128;
  #pragma unroll
  for (int i = 0; i < 4; ++i)
    #pragma unroll
    for (int r = 0; r < 4; ++r) {
      int row = wm*64 + i*16 + l4*4 + r;
      #pragma unroll
      for (int j = 0; j < 4; ++j) {
        int col = wn*64 + j*16 + l15;
        Sb[(size_t)row*NWIN + col] = acc[i][j][r] * scale;
      }
    }
}

// ---------------- row softmax: S f32 -> P bf16 ----------------
__global__ __launch_bounds__(256)
void k_softmax(const float* __restrict__ S, __bf16* __restrict__ P) {
  __shared__ float red[8];
  const int row = blockIdx.x;
  const int t = threadIdx.x;
  const float4 v = ((const float4*)(S + (size_t)row*NWIN))[t];
  float m = fmaxf(fmaxf(v.x, v.y), fmaxf(v.z, v.w));
  for (int off = 1; off < 64; off <<= 1) m = fmaxf(m, __shfl_xor(m, off));
  const int wid = t >> 6, lane = t & 63;
  if (lane == 0) red[wid] = m;
  __syncthreads();
  m = fmaxf(fmaxf(red[0], red[1]), fmaxf(red[2], red[3]));
  float e0 = __expf(v.x - m), e1 = __expf(v.y - m), e2 = __expf(v.z - m), e3 = __expf(v.w - m);
  float s = e0 + e1 + e2 + e3;
  for (int off = 1; off < 64; off <<= 1) s += __shfl_xor(s, off);
  if (lane == 0) red[4 + wid] = s;
  __syncthreads();
  s = red[4] + red[5] + red[6] + red[7];
  float inv = 1.0f / s;
  ushort4 o;
  o.x = bf16u(e0*inv); o.y = bf16u(e1*inv); o.z = bf16u(e2*inv); o.w = bf16u(e3*inv);
  ((ushort4*)((unsigned short*)P + (size_t)row*NWIN))[t] = o;
}

// ---------------- y = P . V  (B = vt[d][m]), scatter to spatial bf16 ----------------
__global__ __launch_bounds__(256)
void k_pv(const __bf16* __restrict__ P, const __bf16* __restrict__ vt,
          __bf16* __restrict__ y) {
  __shared__ __align__(16) unsigned short Asm[4096], Bsm[4096];
  const int bnh = blockIdx.y;
  const int b = bnh >> 2, nh = bnh & 3;
  const int mt = blockIdx.x >> 4, nt = blockIdx.x & 15;
  const __bf16* A = P  + (size_t)bnh*NWIN*NWIN + (size_t)mt*128*NWIN;
  const __bf16* B = vt + (size_t)bnh*DWIN*NWIN + (size_t)nt*128*NWIN;
  f32x4 acc[4][4];
  #pragma unroll
  for (int i = 0; i < 4; ++i)
    #pragma unroll
    for (int j = 0; j < 4; ++j) acc[i][j] = fzero();
  gemm_tile(A, B, NWIN, NWIN, 32, Asm, Bsm, acc);
  const int t = threadIdx.x, lane = t & 63, wid = t >> 6;
  const int wm = wid >> 1, wn = wid & 1, l15 = lane & 15, l4 = lane >> 4;
  #pragma unroll
  for (int i = 0; i < 4; ++i)
    #pragma unroll
    for (int r = 0; r < 4; ++r) {
      int n = mt*128 + wm*64 + i*16 + l4*4 + r;
      int oyy = n >> 5, oxx = n & 31;
      #pragma unroll
      for (int j = 0; j < 4; ++j) {
        int d = nt*128 + wn*64 + j*16 + l15;
        int dk = d >> 6, pyy = (d >> 3) & 7, pxx = d & 7;
        int c = nh*32 + dk, hh = oyy*8 + pyy, ww = oxx*8 + pxx;
        y[(size_t)((b*NCH + c)*IMH + hh)*IMW + ww] = (__bf16)acc[i][j][r];
      }
    }
}

// ---------------- 3x3 reflect conv + bias + LeakyReLU ----------------
// LDS row slot = 128B so the XOR swizzle ((R&7)<<4, up to 0x70) stays in-slot
// (bijective both sides). Previous 64B slot collided rows R%8==7 with R%8==0.
__global__ __launch_bounds__(256)
void k_conv(const __bf16* __restrict__ y, const __bf16* __restrict__ wot,
            const float* __restrict__ bo, float* __restrict__ out) {
  __shared__ __align__(16) unsigned short ylds[3*132*64];  // [row][128B slot] swizzled
  const int bid = blockIdx.x;
  const int half = bid & 1, h = (bid >> 1) & 255, b = bid >> 9;
  const int w0 = half * 128;
  const int t = threadIdx.x;
  const int hm1 = (h == 0) ? 1 : h - 1;
  const int hp1 = (h == 255) ? 254 : h + 1;
  const int lane = t & 63, wid = t >> 6;
  const int wm = wid >> 1, wn = wid & 1, l15 = lane & 15, l4 = lane >> 4;
  f32x4 acc[4][4];
  #pragma unroll
  for (int i = 0; i < 4; ++i)
    #pragma unroll
    for (int j = 0; j < 4; ++j) acc[i][j] = fzero();
  const unsigned short* yu = (const unsigned short*)y;
  for (int cc = 0; cc < 4; ++cc) {
    __syncthreads();
    for (int u = t; u < 3*32*130; u += 256) {
      int wl = u % 130;
      int rc = u / 130;
      int c = rc & 31, rowr = rc >> 5;
      int hh = (rowr == 0) ? hm1 : ((rowr == 1) ? h : hp1);
      int gw = w0 - 1 + wl;
      gw = (gw < 0) ? 1 : ((gw > 255) ? 254 : gw);
      unsigned short val = yu[(size_t)((b*NCH + cc*32 + c)*IMH + hh)*IMW + gw];
      int R = rowr*132 + wl;
      *(unsigned short*)((char*)ylds + R*128 + ((c*2) ^ ((R&7)<<4))) = val;
    }
    __syncthreads();
    #pragma unroll
    for (int kk = 0; kk < 9; ++kk) {
      const int ky = kk / 3, kx = kk % 3;
      bf16x8 a[4], bb[4];
      #pragma unroll
      for (int i = 0; i < 4; ++i) {
        int o = wm*64 + i*16 + l15;
        a[i] = *(const bf16x8*)(wot + ((size_t)kk*128 + o)*128 + cc*32 + l4*8);
      }
      #pragma unroll
      for (int j = 0; j < 4; ++j) {
        int px = wn*64 + j*16 + l15;
        int R = ky*132 + px + kx;
        bb[j] = *(const bf16x8*)((const char*)ylds + R*128 + ((l4*16) ^ ((R&7)<<4)));
      }
      #pragma unroll
      for (int i = 0; i < 4; ++i)
        #pragma unroll
        for (int j = 0; j < 4; ++j)
          acc[i][j] = __builtin_amdgcn_mfma_f32_16x16x32_bf16(a[i], bb[j], acc[i][j], 0, 0, 0);
    }
  }
  #pragma unroll
  for (int i = 0; i < 4; ++i)
    #pragma unroll
    for (int r = 0; r < 4; ++r) {
      int o = wm*64 + i*16 + l4*4 + r;
      float bi = bo[o];
      #pragma unroll
      for (int j = 0; j < 4; ++j) {
        int px = wn*64 + j*16 + l15;
        float v = acc[i][j][r] + bi;
        v = (v > 0.f) ? v : 0.2f * v;
        out[(size_t)((b*NCH + o)*IMH + h)*IMW + w0 + px] = v;
      }
    }
}

// ---------------- launcher ----------------
extern "C" void kernel_launch(void* const* d_in, const int* in_sizes, int n_in,
                              void* d_out, int out_size, void* d_ws, size_t ws_size,
                              hipStream_t stream) {
  (void)in_sizes; (void)n_in; (void)out_size; (void)ws_size;
  const float* x  = (const float*)d_in[0];
  // d_in[1] = m : mask is a no-op in the reference
  const float* wq = (const float*)d_in[2];
  const float* bq = (const float*)d_in[3];
  const float* wk = (const float*)d_in[4];
  const float* bk = (const float*)d_in[5];
  const float* wv = (const float*)d_in[6];
  const float* bv = (const float*)d_in[7];
  const float* wo = (const float*)d_in[8];
  const float* bo = (const float*)d_in[9];
  float* out = (float*)d_out;
  char* ws = (char*)d_ws;
  // region A [0,64MB): qw, later P (first 32MB)
  // region B [64,128MB): kw, later wot (written after scores)
  // region C [128,192MB): vt
  // region D [192,256MB): wt (transient), then S f32, then y bf16
  __bf16* qw  = (__bf16*)(ws + 0);
  __bf16* kw  = (__bf16*)(ws + 67108864);
  __bf16* vt  = (__bf16*)(ws + 134217728);
  float*  S   = (float*)(ws + 201326592);
  __bf16* P   = (__bf16*)(ws + 0);
  __bf16* yb  = (__bf16*)(ws + 201326592);
  __bf16* wt  = (__bf16*)(ws + 201326592);
  __bf16* wot = (__bf16*)(ws + 67108864);

  k_prep_w<<<64, 256, 0, stream>>>(wq, wk, wv, wt);
  k_qkv<<<1024, 512, 0, stream>>>(x, wt, bq, bk, bv, qw, kw, vt);
  k_scores<<<dim3(64, 16), 256, 0, stream>>>(qw, kw, S);
  k_prep_wo<<<576, 256, 0, stream>>>(wo, wot);
  k_softmax<<<16384, 256, 0, stream>>>(S, P);
  k_pv<<<dim3(128, 16), 256, 0, stream>>>(P, vt, yb);
  k_conv<<<2048, 256, 0, stream>>>(yb, wot, bo, out);
}